// Round 4
// baseline (481.201 us; speedup 1.0000x reference)
//
#include <hip/hip_runtime.h>

typedef __bf16 bfrag __attribute__((ext_vector_type(8)));
typedef float f32x4 __attribute__((ext_vector_type(4)));

__device__ __forceinline__ unsigned short f2bf(float f) {
    unsigned int u = __float_as_uint(f);
    unsigned int r = (u + 0x7fffu + ((u >> 16) & 1u)) >> 16;
    return (unsigned short)r;
}
__device__ __forceinline__ float bf2f(unsigned short h) {
    return __uint_as_float(((unsigned int)h) << 16);
}

__device__ __forceinline__ void gll16(const unsigned short* g, unsigned short* l) {
    __builtin_amdgcn_global_load_lds(
        (const __attribute__((address_space(1))) unsigned int*)g,
        (__attribute__((address_space(3))) unsigned int*)l, 16, 0, 0);
}

// ---------------- fused sigmoid-attention ----------------
// O[b, q0:q0+64, :] = sigmoid(Q K^T) V  for one batch b, one 64-row Q tile.
// grid (32, 8) = 256 blocks (1/CU). block = 4 waves.
// LDS layout is "frag-chunk" order: 1KB chunk = one wave's ds_read_b128 fragment
// (chunk*1024 + lane*16) -> gll16-compatible AND conflict-free.
__global__ __launch_bounds__(256, 1) void attn_fused(
    const unsigned short* __restrict__ Q, const unsigned short* __restrict__ K,
    const unsigned short* __restrict__ Vt, unsigned short* __restrict__ O)
{
    __shared__ unsigned short sQ[72 * 512];      // 72 chunks: (mt 0..3) x (ks 0..17)
    __shared__ unsigned short sK[2 * 36 * 512];  // dbuf x 36 chunks: (nt 0..1) x (ks 0..17)
    __shared__ unsigned short sS[4 * 512];       // 4 chunks: A-frag layout of S[64][32]

    const int tid = threadIdx.x;
    const int w   = tid >> 6;
    const int lam = tid & 63;
    const int l15 = lam & 15;
    const int kg  = lam >> 4;
    const size_t bT = (size_t)blockIdx.y * 2048 * 576;
    const int q0 = blockIdx.x * 64;
    const unsigned short* Qb = Q + bT;
    const unsigned short* Kb = K + bT;
    const unsigned short* Vb = Vt + bT;          // [576][2048]

    // stage Q tile (64x576) in frag-chunk order, once
    #pragma unroll
    for (int i = 0; i < 18; ++i) {
        int c = i * 4 + w;                        // chunk = mt*18 + ks
        int mt = c / 18, ks = c % 18;
        gll16(Qb + (size_t)(q0 + mt * 16 + l15) * 576 + ks * 32 + kg * 8,
              &sQ[c * 512 + lam * 8]);
    }
    // stage K tile kt=0
    #pragma unroll
    for (int i = 0; i < 9; ++i) {
        int c = i * 4 + w;                        // chunk = nt*18 + ks
        int nt = c / 18, ks = c % 18;
        gll16(Kb + (size_t)(nt * 16 + l15) * 576 + ks * 32 + kg * 8,
              &sK[c * 512 + lam * 8]);
    }
    __syncthreads();

    f32x4 oacc[4][9] = {};

    for (int kt = 0; kt < 64; ++kt) {
        const int cur = (kt & 1) * 36 * 512;
        const int nxt = ((kt + 1) & 1) * 36 * 512;
        if (kt < 63) {   // async stage next K tile (wave-uniform branch)
            #pragma unroll
            for (int i = 0; i < 9; ++i) {
                int c = i * 4 + w;
                int nt = c / 18, ks = c % 18;
                gll16(Kb + (size_t)((kt + 1) * 32 + nt * 16 + l15) * 576 + ks * 32 + kg * 8,
                      &sK[nxt + c * 512 + lam * 8]);
            }
        }
        // V fragments for this kt, straight from global (L2-resident)
        bfrag vf[9];
        #pragma unroll
        for (int nt = 0; nt < 9; ++nt)
            vf[nt] = *(const bfrag*)(Vb + (size_t)(w * 144 + nt * 16 + l15) * 2048 + kt * 32 + kg * 8);

        // S rows w*16..w*16+16 x 32 tokens: full 576-dot then sigmoid
        f32x4 sacc0 = {}, sacc1 = {};
        #pragma unroll
        for (int ks = 0; ks < 18; ++ks) {
            bfrag qf  = *(const bfrag*)&sQ[(w * 18 + ks) * 512 + lam * 8];
            bfrag kf0 = *(const bfrag*)&sK[cur + ks * 512 + lam * 8];
            bfrag kf1 = *(const bfrag*)&sK[cur + (18 + ks) * 512 + lam * 8];
            sacc0 = __builtin_amdgcn_mfma_f32_16x16x32_bf16(qf, kf0, sacc0, 0, 0, 0);
            sacc1 = __builtin_amdgcn_mfma_f32_16x16x32_bf16(qf, kf1, sacc1, 0, 0, 0);
        }
        // sigmoid + scatter into A-frag layout: element (m, k): lane'=(k>>3)*16+m, short j=k&7
        #pragma unroll
        for (int r = 0; r < 4; ++r) {
            int m = kg * 4 + r;
            float s0 = 1.0f / (1.0f + __expf(-sacc0[r]));
            float s1 = 1.0f / (1.0f + __expf(-sacc1[r]));
            int k0 = l15, k1 = 16 + l15;
            sS[w * 512 + ((k0 >> 3) * 16 + m) * 8 + (k0 & 7)] = f2bf(s0);
            sS[w * 512 + ((k1 >> 3) * 16 + m) * 8 + (k1 & 7)] = f2bf(s1);
        }
        __syncthreads();

        // O[64][576] += S[64][32] * V[32][576]; wave w owns cols w*144..+144
        #pragma unroll
        for (int mt = 0; mt < 4; ++mt) {
            bfrag sf = *(const bfrag*)&sS[mt * 512 + lam * 8];
            #pragma unroll
            for (int nt = 0; nt < 9; ++nt)
                oacc[mt][nt] = __builtin_amdgcn_mfma_f32_16x16x32_bf16(sf, vf[nt], oacc[mt][nt], 0, 0, 0);
        }
        __syncthreads();   // S + K[cur] safe to overwrite
    }

    #pragma unroll
    for (int mt = 0; mt < 4; ++mt)
        #pragma unroll
        for (int nt = 0; nt < 9; ++nt)
            #pragma unroll
            for (int r = 0; r < 4; ++r) {
                int grow = q0 + mt * 16 + kg * 4 + r;
                int gcol = w * 144 + nt * 16 + l15;
                O[bT + (size_t)grow * 576 + gcol] = f2bf(oacc[mt][nt][r]);
            }
}

// ---------------- projection / epilogue GEMM (NT) ----------------
// EPI: 0 = store bf16 (v*scale)
//      2 = +bias[col] + residual bf16 -> f32
//      3 = V-transpose pack: Vt[token>>11][col][token&2047] <- bf16, 8B stores
template<int BM, int BN, int WR, int WC, int EPI>
__global__ __launch_bounds__(256) void gemm_nt(
    const unsigned short* __restrict__ A, const unsigned short* __restrict__ B,
    unsigned short* __restrict__ Cb, float* __restrict__ Cf,
    const unsigned short* __restrict__ R, const float* __restrict__ bias,
    int M, int N, int K, float scale)
{
    constexpr int BK = 32;
    constexpr int WTM = BM / (WR * 16);
    constexpr int WTN = BN / (WC * 16);
    __shared__ unsigned short sA[BM * BK];
    __shared__ unsigned short sB[BN * BK];

    const int tid  = threadIdx.x;
    const int wave = tid >> 6;
    const int lane = tid & 63;
    const int wm = wave / WC;
    const int wn = wave % WC;
    const int bm0 = blockIdx.x * BM;
    const int bn0 = blockIdx.y * BN;
    const int mrow = lane & 15;
    const int kgrp = lane >> 4;

    f32x4 acc[WTM][WTN] = {};

    for (int k0 = 0; k0 < K; k0 += BK) {
        #pragma unroll
        for (int i = 0; i < BM / 64; ++i) {
            int idx = tid + i * 256;
            int r = idx >> 2, c = idx & 3;
            gll16(A + (size_t)(bm0 + r) * K + k0 + c * 8, &sA[idx * 8]);
        }
        #pragma unroll
        for (int i = 0; i < BN / 64; ++i) {
            int idx = tid + i * 256;
            int r = idx >> 2, c = idx & 3;
            gll16(B + (size_t)(bn0 + r) * K + k0 + c * 8, &sB[idx * 8]);
        }
        __syncthreads();

        bfrag af[WTM], bfr[WTN];
        #pragma unroll
        for (int mt = 0; mt < WTM; ++mt)
            af[mt] = *(const bfrag*)&sA[(wm * WTM * 16 + mt * 16 + mrow) * BK + kgrp * 8];
        #pragma unroll
        for (int nt = 0; nt < WTN; ++nt)
            bfr[nt] = *(const bfrag*)&sB[(wn * WTN * 16 + nt * 16 + mrow) * BK + kgrp * 8];
        #pragma unroll
        for (int mt = 0; mt < WTM; ++mt)
            #pragma unroll
            for (int nt = 0; nt < WTN; ++nt)
                acc[mt][nt] = __builtin_amdgcn_mfma_f32_16x16x32_bf16(af[mt], bfr[nt], acc[mt][nt], 0, 0, 0);
        __syncthreads();
    }

    #pragma unroll
    for (int mt = 0; mt < WTM; ++mt) {
        #pragma unroll
        for (int nt = 0; nt < WTN; ++nt) {
            int grow0 = bm0 + wm * WTM * 16 + mt * 16 + kgrp * 4;
            int gcol  = bn0 + wn * WTN * 16 + nt * 16 + mrow;
            if (EPI == 3) {
                ushort4 o;
                o.x = f2bf(acc[mt][nt][0]);
                o.y = f2bf(acc[mt][nt][1]);
                o.z = f2bf(acc[mt][nt][2]);
                o.w = f2bf(acc[mt][nt][3]);
                size_t dst = (((size_t)(grow0 >> 11) * 576 + gcol) << 11) + (grow0 & 2047);
                *(ushort4*)(Cb + dst) = o;
            } else {
                #pragma unroll
                for (int r = 0; r < 4; ++r) {
                    float v = acc[mt][nt][r];
                    size_t off = (size_t)(grow0 + r) * N + gcol;
                    if (EPI == 0) {
                        Cb[off] = f2bf(v * scale);
                    } else {
                        Cf[off] = v + bias[gcol] + bf2f(R[off]);
                    }
                }
            }
        }
    }
}

// LayerNorm over rows of 576 fp32. One wave per row, 4 rows per block.
template<bool OUT_BF>
__global__ __launch_bounds__(256) void ln_rows(
    const float* __restrict__ x, const float* __restrict__ g,
    const float* __restrict__ bb, void* __restrict__ outp)
{
    const int row  = blockIdx.x * 4 + (threadIdx.x >> 6);
    const int lane = threadIdx.x & 63;
    const float* xr = x + (size_t)row * 576;
    float vals[9];
    float s = 0.f, ss = 0.f;
    #pragma unroll
    for (int i = 0; i < 9; ++i) {
        float v = xr[lane + i * 64];
        vals[i] = v; s += v; ss += v * v;
    }
    #pragma unroll
    for (int off = 32; off > 0; off >>= 1) {
        s  += __shfl_xor(s, off, 64);
        ss += __shfl_xor(ss, off, 64);
    }
    float mean = s * (1.0f / 576.0f);
    float var  = ss * (1.0f / 576.0f) - mean * mean;
    float rstd = rsqrtf(var + 1e-5f);
    #pragma unroll
    for (int i = 0; i < 9; ++i) {
        int c = lane + i * 64;
        float o = (vals[i] - mean) * rstd * g[c] + bb[c];
        if (OUT_BF) ((unsigned short*)outp)[(size_t)row * 576 + c] = f2bf(o);
        else        ((float*)outp)[(size_t)row * 576 + c] = o;
    }
}

// 4 weight matrices fp32 -> bf16, blockIdx.y selects which
__global__ __launch_bounds__(256) void cvt4w(
    const float* __restrict__ s0, const float* __restrict__ s1,
    const float* __restrict__ s2, const float* __restrict__ s3,
    unsigned short* __restrict__ dst)
{
    const float* srcs[4] = {s0, s1, s2, s3};
    const float* src = srcs[blockIdx.y];
    unsigned short* d = dst + (size_t)blockIdx.y * 576 * 576;
    int i = (blockIdx.x * 256 + threadIdx.x) * 4;
    float4 f = *(const float4*)(src + i);
    ushort4 o;
    o.x = f2bf(f.x); o.y = f2bf(f.y); o.z = f2bf(f.z); o.w = f2bf(f.w);
    *(ushort4*)(d + i) = o;
}

extern "C" void kernel_launch(void* const* d_in, const int* in_sizes, int n_in,
                              void* d_out, int out_size, void* d_ws, size_t ws_size,
                              hipStream_t stream)
{
    const float* x  = (const float*)d_in[0];
    const float* y  = (const float*)d_in[1];
    const float* Wq = (const float*)d_in[2];
    const float* Wk = (const float*)d_in[3];
    const float* Wv = (const float*)d_in[4];
    const float* Wp = (const float*)d_in[5];
    const float* bp = (const float*)d_in[6];
    const float* gx = (const float*)d_in[7];
    const float* bx = (const float*)d_in[8];
    const float* gy = (const float*)d_in[9];
    const float* by = (const float*)d_in[10];
    const float* gz = (const float*)d_in[11];
    const float* bz = (const float*)d_in[12];

    constexpr size_t WB = 576 * 576 * 2;           // one bf16 weight matrix (bytes)
    constexpr size_t XB = 16384ull * 576 * 2;      // one bf16 activation (bytes)

    char* w = (char*)d_ws;
    unsigned short* wq = (unsigned short*)(w);
    unsigned short* wk = (unsigned short*)(w + WB);
    unsigned short* wv = (unsigned short*)(w + 2 * WB);
    unsigned short* wp = (unsigned short*)(w + 3 * WB);
    unsigned short* xn = (unsigned short*)(w + 4 * WB);
    unsigned short* yn = (unsigned short*)(w + 4 * WB + XB);
    unsigned short* q  = (unsigned short*)(w + 4 * WB + 2 * XB);
    unsigned short* k  = (unsigned short*)(w + 4 * WB + 3 * XB);
    unsigned short* vt = (unsigned short*)(w + 4 * WB + 4 * XB);  // [8][576][2048] bf16
    unsigned short* attno = yn;       // yn dead after q projection
    float* T = (float*)q;             // q,k dead after attention; fp32 T = exactly q+k bytes

    cvt4w<<<dim3(324, 4), 256, 0, stream>>>(Wq, Wk, Wv, Wp, wq);

    ln_rows<true><<<4096, 256, 0, stream>>>(x, gx, bx, xn);
    ln_rows<true><<<4096, 256, 0, stream>>>(y, gy, by, yn);

    const float SCALE = 0.041666666666666664f;  // 576^-0.5 = 1/24, folded into q
    gemm_nt<256, 64, 4, 1, 0><<<dim3(64, 9), 256, 0, stream>>>(
        yn, wq, q, nullptr, nullptr, nullptr, 16384, 576, 576, SCALE);
    gemm_nt<256, 64, 4, 1, 0><<<dim3(64, 9), 256, 0, stream>>>(
        xn, wk, k, nullptr, nullptr, nullptr, 16384, 576, 576, 1.0f);
    gemm_nt<256, 64, 4, 1, 3><<<dim3(64, 9), 256, 0, stream>>>(
        xn, wv, vt, nullptr, nullptr, nullptr, 16384, 576, 576, 1.0f);

    // fused sigmoid-attention: O = sigmoid(q k^T) v, all 8 batches
    attn_fused<<<dim3(32, 8), 256, 0, stream>>>(q, k, vt, attno);

    // T = attno * Wp^T + bp + xn   (fp32)
    gemm_nt<256, 64, 4, 1, 2><<<dim3(64, 9), 256, 0, stream>>>(
        attno, wp, nullptr, T, xn, bp, 16384, 576, 576, 1.0f);
    // out = LN(T) (fp32)
    ln_rows<false><<<4096, 256, 0, stream>>>(T, gz, bz, d_out);
}

// Round 5
// 371.497 us; speedup vs baseline: 1.2953x; 1.2953x over previous
//
#include <hip/hip_runtime.h>

typedef __bf16 bfrag __attribute__((ext_vector_type(8)));
typedef float f32x4 __attribute__((ext_vector_type(4)));

__device__ __forceinline__ unsigned short f2bf(float f) {
    unsigned int u = __float_as_uint(f);
    unsigned int r = (u + 0x7fffu + ((u >> 16) & 1u)) >> 16;
    return (unsigned short)r;
}
__device__ __forceinline__ float bf2f(unsigned short h) {
    return __uint_as_float(((unsigned int)h) << 16);
}

__device__ __forceinline__ void gll16(const unsigned short* g, unsigned short* l) {
    __builtin_amdgcn_global_load_lds(
        (const __attribute__((address_space(1))) unsigned int*)g,
        (__attribute__((address_space(3))) unsigned int*)l, 16, 0, 0);
}

// ---------------- generic NT GEMM ----------------
// C = A[M,K] * B^T, B is [N,K]. z-batched via element strides.
// EPI: 0 = store bf16 (v*scale); 1 = sigmoid -> bf16; 2 = +bias[col]+residual bf16 -> f32
template<int BM, int BN, int WR, int WC, int EPI>
__global__ __launch_bounds__(256) void gemm_nt(
    const unsigned short* __restrict__ A, const unsigned short* __restrict__ B,
    unsigned short* __restrict__ Cb, float* __restrict__ Cf,
    const unsigned short* __restrict__ R, const float* __restrict__ bias,
    int M, int N, int K, float scale,
    size_t sAz, size_t sBz, size_t sCz)
{
    constexpr int BK = 32;
    constexpr int WTM = BM / (WR * 16);
    constexpr int WTN = BN / (WC * 16);
    __shared__ unsigned short sA[BM * BK];
    __shared__ unsigned short sB[BN * BK];

    A += blockIdx.z * sAz;
    B += blockIdx.z * sBz;

    const int tid  = threadIdx.x;
    const int wave = tid >> 6;
    const int lane = tid & 63;
    const int wm = wave / WC;
    const int wn = wave % WC;
    const int bm0 = blockIdx.x * BM;
    const int bn0 = blockIdx.y * BN;
    const int mrow = lane & 15;
    const int kgrp = lane >> 4;

    f32x4 acc[WTM][WTN] = {};

    for (int k0 = 0; k0 < K; k0 += BK) {
        #pragma unroll
        for (int i = 0; i < BM / 64; ++i) {
            int idx = tid + i * 256;
            int r = idx >> 2, c = idx & 3;
            gll16(A + (size_t)(bm0 + r) * K + k0 + c * 8, &sA[idx * 8]);
        }
        #pragma unroll
        for (int i = 0; i < BN / 64; ++i) {
            int idx = tid + i * 256;
            int r = idx >> 2, c = idx & 3;
            gll16(B + (size_t)(bn0 + r) * K + k0 + c * 8, &sB[idx * 8]);
        }
        __syncthreads();

        bfrag af[WTM], bfr[WTN];
        #pragma unroll
        for (int mt = 0; mt < WTM; ++mt)
            af[mt] = *(const bfrag*)&sA[(wm * WTM * 16 + mt * 16 + mrow) * BK + kgrp * 8];
        #pragma unroll
        for (int nt = 0; nt < WTN; ++nt)
            bfr[nt] = *(const bfrag*)&sB[(wn * WTN * 16 + nt * 16 + mrow) * BK + kgrp * 8];
        #pragma unroll
        for (int mt = 0; mt < WTM; ++mt)
            #pragma unroll
            for (int nt = 0; nt < WTN; ++nt)
                acc[mt][nt] = __builtin_amdgcn_mfma_f32_16x16x32_bf16(af[mt], bfr[nt], acc[mt][nt], 0, 0, 0);
        __syncthreads();
    }

    #pragma unroll
    for (int mt = 0; mt < WTM; ++mt) {
        #pragma unroll
        for (int nt = 0; nt < WTN; ++nt) {
            int grow0 = bm0 + wm * WTM * 16 + mt * 16 + kgrp * 4;
            int gcol  = bn0 + wn * WTN * 16 + nt * 16 + mrow;
            #pragma unroll
            for (int r = 0; r < 4; ++r) {
                float v = acc[mt][nt][r];
                size_t off = blockIdx.z * sCz + (size_t)(grow0 + r) * N + gcol;
                if (EPI == 0) {
                    Cb[off] = f2bf(v * scale);
                } else if (EPI == 1) {
                    Cb[off] = f2bf(1.0f / (1.0f + __expf(-v)));
                } else {
                    Cf[off] = v + bias[gcol] + bf2f(R[off]);
                }
            }
        }
    }
}

// ---------------- fused QKV projection ----------------
// z=0: q = (yn Wq^T)*SCALE ; z=1: k = xn Wk^T ; z=2: vt-pack of xn Wv^T
__global__ __launch_bounds__(256) void qkv_proj(
    const unsigned short* __restrict__ xn, const unsigned short* __restrict__ yn,
    const unsigned short* __restrict__ W,   // [3][576][576] bf16 (wq,wk,wv)
    unsigned short* __restrict__ qk,        // q then k, contiguous [2][16384][576]
    unsigned short* __restrict__ vt,        // [8][576][2048]
    float scale)
{
    constexpr int BM = 128, BN = 64, BK = 32;
    __shared__ unsigned short sA[BM * BK];
    __shared__ unsigned short sB[BN * BK];

    const int z = blockIdx.z;
    const unsigned short* A = (z == 0) ? yn : xn;
    const unsigned short* B = W + (size_t)z * 576 * 576;
    const float sc = (z == 0) ? scale : 1.0f;

    const int tid  = threadIdx.x;
    const int wave = tid >> 6;
    const int lane = tid & 63;
    const int wm = wave >> 1;   // WR=2
    const int wn = wave & 1;    // WC=2
    const int bm0 = blockIdx.x * BM;
    const int bn0 = blockIdx.y * BN;
    const int mrow = lane & 15;
    const int kgrp = lane >> 4;
    constexpr int WTM = 4, WTN = 2;

    f32x4 acc[WTM][WTN] = {};

    for (int k0 = 0; k0 < 576; k0 += BK) {
        #pragma unroll
        for (int i = 0; i < BM / 64; ++i) {
            int idx = tid + i * 256;
            int r = idx >> 2, c = idx & 3;
            gll16(A + (size_t)(bm0 + r) * 576 + k0 + c * 8, &sA[idx * 8]);
        }
        {
            int r = tid >> 2, c = tid & 3;
            gll16(B + (size_t)(bn0 + r) * 576 + k0 + c * 8, &sB[tid * 8]);
        }
        __syncthreads();

        bfrag af[WTM], bfr[WTN];
        #pragma unroll
        for (int mt = 0; mt < WTM; ++mt)
            af[mt] = *(const bfrag*)&sA[(wm * WTM * 16 + mt * 16 + mrow) * BK + kgrp * 8];
        #pragma unroll
        for (int nt = 0; nt < WTN; ++nt)
            bfr[nt] = *(const bfrag*)&sB[(wn * WTN * 16 + nt * 16 + mrow) * BK + kgrp * 8];
        #pragma unroll
        for (int mt = 0; mt < WTM; ++mt)
            #pragma unroll
            for (int nt = 0; nt < WTN; ++nt)
                acc[mt][nt] = __builtin_amdgcn_mfma_f32_16x16x32_bf16(af[mt], bfr[nt], acc[mt][nt], 0, 0, 0);
        __syncthreads();
    }

    #pragma unroll
    for (int mt = 0; mt < WTM; ++mt) {
        #pragma unroll
        for (int nt = 0; nt < WTN; ++nt) {
            int grow0 = bm0 + wm * WTM * 16 + mt * 16 + kgrp * 4;
            int gcol  = bn0 + wn * WTN * 16 + nt * 16 + mrow;
            if (z == 2) {
                ushort4 o;
                o.x = f2bf(acc[mt][nt][0]);
                o.y = f2bf(acc[mt][nt][1]);
                o.z = f2bf(acc[mt][nt][2]);
                o.w = f2bf(acc[mt][nt][3]);
                size_t dst = (((size_t)(grow0 >> 11) * 576 + gcol) << 11) + (grow0 & 2047);
                *(ushort4*)(vt + dst) = o;
            } else {
                unsigned short* C = qk + (size_t)z * 16384 * 576;
                #pragma unroll
                for (int r = 0; r < 4; ++r)
                    C[(size_t)(grow0 + r) * 576 + gcol] = f2bf(acc[mt][nt][r] * sc);
            }
        }
    }
}

// ---------------- LayerNorm ----------------
// Fused pair: grid.y=0 -> LN(x;gx,bx)->xn(bf16); grid.y=1 -> LN(y;gy,by)->yn(bf16)
__global__ __launch_bounds__(256) void ln_pair(
    const float* __restrict__ x, const float* __restrict__ gx, const float* __restrict__ bx,
    unsigned short* __restrict__ xn,
    const float* __restrict__ y, const float* __restrict__ gy, const float* __restrict__ by,
    unsigned short* __restrict__ yn)
{
    const float* src = blockIdx.y ? y : x;
    const float* g   = blockIdx.y ? gy : gx;
    const float* bb  = blockIdx.y ? by : bx;
    unsigned short* o = blockIdx.y ? yn : xn;

    const int row  = blockIdx.x * 4 + (threadIdx.x >> 6);
    const int lane = threadIdx.x & 63;
    const float* xr = src + (size_t)row * 576;
    float vals[9];
    float s = 0.f, ss = 0.f;
    #pragma unroll
    for (int i = 0; i < 9; ++i) {
        float v = xr[lane + i * 64];
        vals[i] = v; s += v; ss += v * v;
    }
    #pragma unroll
    for (int off = 32; off > 0; off >>= 1) {
        s  += __shfl_xor(s, off, 64);
        ss += __shfl_xor(ss, off, 64);
    }
    float mean = s * (1.0f / 576.0f);
    float var  = ss * (1.0f / 576.0f) - mean * mean;
    float rstd = rsqrtf(var + 1e-5f);
    #pragma unroll
    for (int i = 0; i < 9; ++i) {
        int c = lane + i * 64;
        o[(size_t)row * 576 + c] = f2bf((vals[i] - mean) * rstd * g[c] + bb[c]);
    }
}

// Final LN: fp32 in -> fp32 out
__global__ __launch_bounds__(256) void ln_final(
    const float* __restrict__ x, const float* __restrict__ g,
    const float* __restrict__ bb, float* __restrict__ outp)
{
    const int row  = blockIdx.x * 4 + (threadIdx.x >> 6);
    const int lane = threadIdx.x & 63;
    const float* xr = x + (size_t)row * 576;
    float vals[9];
    float s = 0.f, ss = 0.f;
    #pragma unroll
    for (int i = 0; i < 9; ++i) {
        float v = xr[lane + i * 64];
        vals[i] = v; s += v; ss += v * v;
    }
    #pragma unroll
    for (int off = 32; off > 0; off >>= 1) {
        s  += __shfl_xor(s, off, 64);
        ss += __shfl_xor(ss, off, 64);
    }
    float mean = s * (1.0f / 576.0f);
    float var  = ss * (1.0f / 576.0f) - mean * mean;
    float rstd = rsqrtf(var + 1e-5f);
    #pragma unroll
    for (int i = 0; i < 9; ++i) {
        int c = lane + i * 64;
        outp[(size_t)row * 576 + c] = (vals[i] - mean) * rstd * g[c] + bb[c];
    }
}

// 4 weight matrices fp32 -> bf16, blockIdx.y selects which
__global__ __launch_bounds__(256) void cvt4w(
    const float* __restrict__ s0, const float* __restrict__ s1,
    const float* __restrict__ s2, const float* __restrict__ s3,
    unsigned short* __restrict__ dst)
{
    const float* srcs[4] = {s0, s1, s2, s3};
    const float* src = srcs[blockIdx.y];
    unsigned short* d = dst + (size_t)blockIdx.y * 576 * 576;
    int i = (blockIdx.x * 256 + threadIdx.x) * 4;
    float4 f = *(const float4*)(src + i);
    ushort4 o;
    o.x = f2bf(f.x); o.y = f2bf(f.y); o.z = f2bf(f.z); o.w = f2bf(f.w);
    *(ushort4*)(d + i) = o;
}

extern "C" void kernel_launch(void* const* d_in, const int* in_sizes, int n_in,
                              void* d_out, int out_size, void* d_ws, size_t ws_size,
                              hipStream_t stream)
{
    const float* x  = (const float*)d_in[0];
    const float* y  = (const float*)d_in[1];
    const float* Wq = (const float*)d_in[2];
    const float* Wk = (const float*)d_in[3];
    const float* Wv = (const float*)d_in[4];
    const float* Wp = (const float*)d_in[5];
    const float* bp = (const float*)d_in[6];
    const float* gx = (const float*)d_in[7];
    const float* bx = (const float*)d_in[8];
    const float* gy = (const float*)d_in[9];
    const float* by = (const float*)d_in[10];
    const float* gz = (const float*)d_in[11];
    const float* bz = (const float*)d_in[12];

    constexpr size_t WB = 576 * 576 * 2;           // one bf16 weight matrix (bytes)
    constexpr size_t XB = 16384ull * 576 * 2;      // one bf16 activation (bytes)
    constexpr size_t TOK = (size_t)2048 * 576;     // elements per batch of activation
    constexpr size_t SB  = (size_t)2048 * 2048;    // elements per batch of S

    char* w = (char*)d_ws;
    unsigned short* wq = (unsigned short*)(w);          // wq,wk,wv,wp contiguous
    unsigned short* wp = (unsigned short*)(w + 3 * WB);
    unsigned short* xn = (unsigned short*)(w + 4 * WB);
    unsigned short* yn = (unsigned short*)(w + 4 * WB + XB);
    unsigned short* q  = (unsigned short*)(w + 4 * WB + 2 * XB);  // q then k contiguous
    unsigned short* k  = (unsigned short*)(w + 4 * WB + 3 * XB);
    unsigned short* vt = (unsigned short*)(w + 4 * WB + 4 * XB);  // [8][576][2048]
    unsigned short* S  = (unsigned short*)(w + 4 * WB + 5 * XB);  // [8][2048][2048], 67 MB
    unsigned short* attno = yn;       // yn dead after q projection
    float* T = (float*)q;             // q,k dead after attention; fp32 T = exactly q+k bytes

    cvt4w<<<dim3(324, 4), 256, 0, stream>>>(Wq, Wk, Wv, Wp, wq);

    ln_pair<<<dim3(4096, 2), 256, 0, stream>>>(x, gx, bx, xn, y, gy, by, yn);

    const float SCALE = 0.041666666666666664f;  // 576^-0.5 = 1/24, folded into q
    // q/k/v projections, one launch (z selects), grid 3456 blocks
    qkv_proj<<<dim3(128, 9, 3), 256, 0, stream>>>(xn, yn, wq, q, vt, SCALE);

    // S_b = sigmoid(q_b k_b^T)  [2048 x 2048] x 8, grid 2048 blocks
    gemm_nt<128, 128, 2, 2, 1><<<dim3(16, 16, 8), 256, 0, stream>>>(
        q, k, S, nullptr, nullptr, nullptr, 2048, 2048, 576, 1.0f, TOK, TOK, SB);
    // O_b = S_b v_b  (NT vs Vt)  [2048 x 576] x 8, grid 1152 blocks
    gemm_nt<128, 64, 2, 2, 0><<<dim3(16, 9, 8), 256, 0, stream>>>(
        S, vt, attno, nullptr, nullptr, nullptr, 2048, 576, 2048, 1.0f, SB, TOK, TOK);

    // T = attno Wp^T + bp + xn  (fp32), grid 1152 blocks
    gemm_nt<128, 64, 2, 2, 2><<<dim3(128, 9, 1), 256, 0, stream>>>(
        attno, wp, nullptr, T, xn, bp, 16384, 576, 576, 1.0f, 0, 0, 0);
    // out = LN(T)
    ln_final<<<4096, 256, 0, stream>>>(T, gz, bz, (float*)d_out);
}